// Round 3
// baseline (1134.708 us; speedup 1.0000x reference)
//
#include <hip/hip_runtime.h>

static constexpr int ID  = 128;   // IN_DIM
static constexpr int ND  = 32;    // NET_DIM
static constexpr int NPB = 128;   // nodes per bucket (lcol fits 7 bits)
static constexpr int CPAD = 16;   // u32s per bucket cursor (one 64B line each)

// ---- deg count: one int atomic per edge at target ----
__global__ __launch_bounds__(256) void k_count(const int* __restrict__ col, int E,
                                               unsigned* __restrict__ cnt) {
    int e = blockIdx.x * 256 + threadIdx.x;
    if (e < E) atomicAdd(&cnt[col[e]], 1u);
}

// ---- per-bucket sums of cnt (128 nodes/bucket) + dinv = rsqrt(deg+1) ----
__global__ __launch_bounds__(128) void k_bsum_dinv(const unsigned* __restrict__ cnt, int n,
                                                   unsigned* __restrict__ bsize,
                                                   float* __restrict__ dinv) {
    __shared__ unsigned s[128];
    int i = blockIdx.x * 128 + threadIdx.x;
    unsigned v = (i < n) ? cnt[i] : 0u;
    s[threadIdx.x] = v;
    if (i < n) dinv[i] = rsqrtf((float)(v + 1u));
    __syncthreads();
    for (int d = 64; d > 0; d >>= 1) {
        if (threadIdx.x < d) s[threadIdx.x] += s[threadIdx.x + d];
        __syncthreads();
    }
    if (threadIdx.x == 0) bsize[blockIdx.x] = s[0];
}

// ---- exclusive scan of bucket sizes (single block); init padded cursors ----
__global__ __launch_bounds__(1024) void k_scan(const unsigned* __restrict__ bsize, int B,
                                               unsigned* __restrict__ boff,
                                               unsigned* __restrict__ bcur) {
    __shared__ unsigned s[1024];
    int t = threadIdx.x;
    unsigned v0 = (t < B) ? bsize[t] : 0u;
    s[t] = v0;
    __syncthreads();
    for (int d = 1; d < 1024; d <<= 1) {
        unsigned v = (t >= d) ? s[t - d] : 0u;
        __syncthreads();
        s[t] += v;
        __syncthreads();
    }
    if (t < B) {
        unsigned off = s[t] - v0;   // exclusive
        boff[t] = off;
        bcur[t * CPAD] = off;
    }
}

// ---- hs = dinv[i] * (x[i] @ W_gcn) ----
__global__ __launch_bounds__(256) void k_gemm(const float* __restrict__ x,
                                              const float* __restrict__ W,
                                              const float* __restrict__ dinv,
                                              float* __restrict__ hs, int n) {
    __shared__ float sW[ID * ND];        // 16 KB, [k][j]
    for (int i = threadIdx.x; i < ID * ND; i += 256) sW[i] = W[i];
    __syncthreads();
    int row = blockIdx.x * 256 + threadIdx.x;
    if (row >= n) return;
    float acc[ND];
#pragma unroll
    for (int j = 0; j < ND; ++j) acc[j] = 0.f;
    const float4* xr = reinterpret_cast<const float4*>(x + (size_t)row * ID);
    for (int k4 = 0; k4 < ID / 4; ++k4) {
        float4 v = xr[k4];
        const float* w0 = &sW[(k4 * 4 + 0) * ND];
        const float* w1 = &sW[(k4 * 4 + 1) * ND];
        const float* w2 = &sW[(k4 * 4 + 2) * ND];
        const float* w3 = &sW[(k4 * 4 + 3) * ND];
#pragma unroll
        for (int j = 0; j < ND; ++j)
            acc[j] += v.x * w0[j] + v.y * w1[j] + v.z * w2[j] + v.w * w3[j];
    }
    float di = dinv[row];
    float4* hp = reinterpret_cast<float4*>(hs + (size_t)row * ND);
#pragma unroll
    for (int q = 0; q < ND / 4; ++q) {
        float4 o;
        o.x = di * acc[q * 4 + 0];
        o.y = di * acc[q * 4 + 1];
        o.z = di * acc[q * 4 + 2];
        o.w = di * acc[q * 4 + 3];
        hp[q] = o;
    }
}

// ---- binning: packed[p] = (lcol<<17)|row, appended per 128-node bucket ----
__global__ __launch_bounds__(256) void k_bucket(const int* __restrict__ row,
                                                const int* __restrict__ col,
                                                unsigned* __restrict__ bcur,
                                                unsigned* __restrict__ packed, int E) {
    int e = blockIdx.x * 256 + threadIdx.x;
    if (e < E) {
        int c = col[e];
        int b = c >> 7;                       // /NPB
        unsigned p = atomicAdd(&bcur[b * CPAD], 1u);
        packed[p] = ((unsigned)(c & (NPB - 1)) << 17) | (unsigned)row[e];
    }
}

// ---- fused: LDS-aggregate bucket edges + self-loop + dinv/bias/relu/dense/relu ----
__global__ __launch_bounds__(512) void k_agg(const unsigned* __restrict__ boff,
                                             const unsigned* __restrict__ bsize,
                                             const unsigned* __restrict__ packed,
                                             const float* __restrict__ hs,
                                             const float* __restrict__ dinv,
                                             const float* __restrict__ bg,
                                             const float* __restrict__ Wd,
                                             const float* __restrict__ bd,
                                             float* __restrict__ out, int n) {
    __shared__ float agg[NPB * ND];   // 16 KB
    __shared__ float sW[ND * ND];     // 4 KB
    __shared__ float sbg[ND];
    __shared__ float sbd[ND];
    int tid = threadIdx.x;
    for (int i = tid; i < NPB * ND; i += 512) agg[i] = 0.f;
    for (int i = tid; i < ND * ND; i += 512) sW[i] = Wd[i];
    if (tid < ND) { sbg[tid] = bg[tid]; sbd[tid] = bd[tid]; }
    __syncthreads();

    int b = blockIdx.x;
    unsigned base = boff[b];
    unsigned m = bsize[b];
    int ch  = tid & 31;
    int g32 = tid >> 5;                 // 16 groups of 32 lanes
    for (unsigned k = g32; k < m; k += 16) {
        unsigned e = packed[base + k];  // uniform within group -> broadcast
        unsigned r  = e & 0x1FFFFu;
        unsigned lc = e >> 17;
        float v = hs[(size_t)r * ND + ch];          // 128B contiguous gather
        atomicAdd(&agg[lc * ND + ch], v);           // ds_add_f32, conflict-free
    }
    __syncthreads();

    // finalize 128 nodes: 8 waves x 2 nodes per iter
    int wave = tid >> 6;
    int half = (tid & 63) >> 5;
    int nodebase = b * NPB;
    for (int lp = wave; lp < NPB / 2; lp += 8) {
        int lc = lp * 2 + half;
        int c = nodebase + lc;
        if (c < n) {
            float di = dinv[c];
            float acc = agg[lc * ND + ch] + hs[(size_t)c * ND + ch];  // edges + self
            float g = fmaxf(di * acc + sbg[ch], 0.f);
            float o = sbd[ch];
#pragma unroll
            for (int j = 0; j < ND; ++j) {
                float gj = __shfl(g, j, 32);
                o += gj * sW[j * ND + ch];
            }
            out[(size_t)c * ND + ch] = fmaxf(o, 0.f);
        }
    }
}

extern "C" void kernel_launch(void* const* d_in, const int* in_sizes, int n_in,
                              void* d_out, int out_size, void* d_ws, size_t ws_size,
                              hipStream_t stream) {
    const float* x  = (const float*)d_in[0];
    const int*   ei = (const int*)d_in[1];   // [2, E] flat: row then col
    const float* Wg = (const float*)d_in[2];
    const float* bg = (const float*)d_in[3];
    const float* Wd = (const float*)d_in[4];
    const float* bd = (const float*)d_in[5];
    float* out = (float*)d_out;

    const int n = in_sizes[0] / ID;        // 100000
    const int E = in_sizes[1] / 2;         // 3200000
    const int* erow = ei;
    const int* ecol = ei + E;
    const int B = (n + NPB - 1) / NPB;     // 782 buckets

    // workspace carve-up
    float*    hs     = (float*)d_ws;                        // n*ND f32   (12.8 MB)
    unsigned* packed = (unsigned*)(hs + (size_t)n * ND);    // E u32      (12.8 MB)
    unsigned* cnt    = packed + (size_t)E;                  // n u32
    float*    dinv   = (float*)(cnt + n);                   // n f32
    unsigned* bsize  = (unsigned*)(dinv + n);               // B u32
    unsigned* boff   = bsize + B;                           // B u32
    unsigned* bcur   = boff + B;                            // B*CPAD u32 (50 KB)

    hipMemsetAsync(cnt, 0, (size_t)n * sizeof(unsigned), stream);
    k_count<<<(E + 255) / 256, 256, 0, stream>>>(ecol, E, cnt);
    k_bsum_dinv<<<B, 128, 0, stream>>>(cnt, n, bsize, dinv);
    k_scan<<<1, 1024, 0, stream>>>(bsize, B, boff, bcur);
    k_gemm<<<(n + 255) / 256, 256, 0, stream>>>(x, Wg, dinv, hs, n);
    k_bucket<<<(E + 255) / 256, 256, 0, stream>>>(erow, ecol, bcur, packed, E);
    k_agg<<<B, 512, 0, stream>>>(boff, bsize, packed, hs, dinv, bg, Wd, bd, out, n);
}

// Round 4
// 967.530 us; speedup vs baseline: 1.1728x; 1.1728x over previous
//
#include <hip/hip_runtime.h>

static constexpr int ID   = 128;   // IN_DIM
static constexpr int ND   = 32;    // NET_DIM
static constexpr int NPB  = 64;    // nodes per bucket (lc fits 6 bits)
static constexpr int CPAD = 16;    // u32s per bucket cursor (64B line each)
static constexpr int EPB  = 8192;  // edges per k_place block
static constexpr int EPT  = 32;    // edges per thread in k_place (256 thr)
static constexpr int BMAX = 1600;  // >= ceil(100000/64)=1563

// ---- deg count: one int atomic per edge at target ----
__global__ __launch_bounds__(256) void k_count(const int* __restrict__ col, int E,
                                               unsigned* __restrict__ cnt) {
    int e = blockIdx.x * 256 + threadIdx.x;
    if (e < E) atomicAdd(&cnt[col[e]], 1u);
}

// ---- per-bucket sums of cnt (64 nodes/bucket) + dinv = rsqrt(deg+1) ----
__global__ __launch_bounds__(64) void k_bsum_dinv(const unsigned* __restrict__ cnt, int n,
                                                  unsigned* __restrict__ bsize,
                                                  float* __restrict__ dinv) {
    int i = blockIdx.x * 64 + threadIdx.x;
    unsigned v = (i < n) ? cnt[i] : 0u;
    if (i < n) dinv[i] = rsqrtf((float)(v + 1u));
    unsigned s = v;
#pragma unroll
    for (int d = 1; d < 64; d <<= 1) s += (unsigned)__shfl_xor((int)s, d);
    if (threadIdx.x == 0) bsize[blockIdx.x] = s;
}

// ---- exclusive scan of bucket sizes (1 block, 2 elems/thread, B<=2048) ----
__global__ __launch_bounds__(1024) void k_scan(const unsigned* __restrict__ bsize, int B,
                                               unsigned* __restrict__ boff,
                                               unsigned* __restrict__ bcur) {
    __shared__ unsigned s[1024];
    int t = threadIdx.x;
    int i0 = 2 * t, i1 = 2 * t + 1;
    unsigned a  = (i0 < B) ? bsize[i0] : 0u;
    unsigned b2 = (i1 < B) ? bsize[i1] : 0u;
    s[t] = a + b2;
    __syncthreads();
    for (int d = 1; d < 1024; d <<= 1) {
        unsigned v = (t >= d) ? s[t - d] : 0u;
        __syncthreads();
        s[t] += v;
        __syncthreads();
    }
    unsigned excl = s[t] - (a + b2);
    if (i0 < B) { boff[i0] = excl;     bcur[(size_t)i0 * CPAD] = excl; }
    if (i1 < B) { boff[i1] = excl + a; bcur[(size_t)i1 * CPAD] = excl + a; }
}

// ---- hs = dinv[i] * (x[i] @ W_gcn) ----
__global__ __launch_bounds__(256) void k_gemm(const float* __restrict__ x,
                                              const float* __restrict__ W,
                                              const float* __restrict__ dinv,
                                              float* __restrict__ hs, int n) {
    __shared__ float sW[ID * ND];        // 16 KB, [k][j]
    for (int i = threadIdx.x; i < ID * ND; i += 256) sW[i] = W[i];
    __syncthreads();
    int row = blockIdx.x * 256 + threadIdx.x;
    if (row >= n) return;
    float acc[ND];
#pragma unroll
    for (int j = 0; j < ND; ++j) acc[j] = 0.f;
    const float4* xr = reinterpret_cast<const float4*>(x + (size_t)row * ID);
    for (int k4 = 0; k4 < ID / 4; ++k4) {
        float4 v = xr[k4];
        const float* w0 = &sW[(k4 * 4 + 0) * ND];
        const float* w1 = &sW[(k4 * 4 + 1) * ND];
        const float* w2 = &sW[(k4 * 4 + 2) * ND];
        const float* w3 = &sW[(k4 * 4 + 3) * ND];
#pragma unroll
        for (int j = 0; j < ND; ++j)
            acc[j] += v.x * w0[j] + v.y * w1[j] + v.z * w2[j] + v.w * w3[j];
    }
    float di = dinv[row];
    float4* hp = reinterpret_cast<float4*>(hs + (size_t)row * ND);
#pragma unroll
    for (int q = 0; q < ND / 4; ++q) {
        float4 o;
        o.x = di * acc[q * 4 + 0];
        o.y = di * acc[q * 4 + 1];
        o.z = di * acc[q * 4 + 2];
        o.w = di * acc[q * 4 + 3];
        hp[q] = o;
    }
}

// ---- binning, two-phase per block: LDS count -> one reserve atomic per
//      (block,bucket) -> place into reserved chunk (consecutive writes) ----
__global__ __launch_bounds__(256) void k_place(const int* __restrict__ row,
                                               const int* __restrict__ col,
                                               unsigned* __restrict__ bcur,
                                               unsigned* __restrict__ packed,
                                               int E, int B) {
    __shared__ unsigned lcnt[BMAX];
    __shared__ unsigned lbase[BMAX];
    int tid = threadIdx.x;
    for (int i = tid; i < B; i += 256) lcnt[i] = 0u;
    __syncthreads();
    long base = (long)blockIdx.x * EPB;
    int colv[EPT];
#pragma unroll
    for (int i = 0; i < EPT; ++i) {
        long e = base + tid + i * 256;
        int c = (e < E) ? col[e] : -1;
        colv[i] = c;
        if (c >= 0) atomicAdd(&lcnt[c >> 6], 1u);
    }
    __syncthreads();
    for (int b = tid; b < B; b += 256) {
        unsigned v = lcnt[b];
        lbase[b] = v ? atomicAdd(&bcur[(size_t)b * CPAD], v) : 0u;
        lcnt[b] = 0u;   // reuse as local placement cursor
    }
    __syncthreads();
#pragma unroll
    for (int i = 0; i < EPT; ++i) {
        long e = base + tid + i * 256;
        if (e < E) {
            int c = colv[i];
            int b = c >> 6;
            unsigned lofs = atomicAdd(&lcnt[b], 1u);
            packed[lbase[b] + lofs] = ((unsigned)(c & (NPB - 1)) << 17) | (unsigned)row[e];
        }
    }
}

// ---- fused gather + LDS aggregate + finalize (dinv/bias/relu/dense/relu) ----
// 64-lane wave = 8 edges x 8 lanes x float4; unroll x4 for ILP.
__global__ __launch_bounds__(256) void k_agg(const unsigned* __restrict__ boff,
                                             const unsigned* __restrict__ bsize,
                                             const unsigned* __restrict__ packed,
                                             const float* __restrict__ hs,
                                             const float* __restrict__ dinv,
                                             const float* __restrict__ bg,
                                             const float* __restrict__ Wd,
                                             const float* __restrict__ bd,
                                             float* __restrict__ out, int n) {
    __shared__ float agg[NPB * ND];   // 8 KB
    __shared__ float sW[ND * ND];     // 4 KB
    __shared__ float sbg[ND];
    __shared__ float sbd[ND];
    int tid = threadIdx.x;
    for (int i = tid; i < NPB * ND; i += 256) agg[i] = 0.f;
    for (int i = tid; i < ND * ND; i += 256) sW[i] = Wd[i];
    if (tid < ND) { sbg[tid] = bg[tid]; sbd[tid] = bd[tid]; }
    __syncthreads();

    int b = blockIdx.x;
    unsigned base = boff[b];
    unsigned m = bsize[b];
    int w   = tid >> 6;            // wave 0..3
    int sub = (tid & 63) >> 3;     // edge slot within wave 0..7
    int l8  = tid & 7;             // channel quad 0..7
    const float4* hs4 = reinterpret_cast<const float4*>(hs);

    for (unsigned k = (unsigned)w * 32u; k < m; k += 128u) {
        unsigned i0 = k + 0u * 8u + (unsigned)sub;
        unsigned i1 = k + 1u * 8u + (unsigned)sub;
        unsigned i2 = k + 2u * 8u + (unsigned)sub;
        unsigned i3 = k + 3u * 8u + (unsigned)sub;
        bool g0 = i0 < m, g1 = i1 < m, g2 = i2 < m, g3 = i3 < m;
        unsigned e0 = g0 ? packed[base + i0] : 0u;
        unsigned e1 = g1 ? packed[base + i1] : 0u;
        unsigned e2 = g2 ? packed[base + i2] : 0u;
        unsigned e3 = g3 ? packed[base + i3] : 0u;
        float4 v0 = hs4[(size_t)(e0 & 0x1FFFFu) * 8 + l8];   // always-valid addr
        float4 v1 = hs4[(size_t)(e1 & 0x1FFFFu) * 8 + l8];
        float4 v2 = hs4[(size_t)(e2 & 0x1FFFFu) * 8 + l8];
        float4 v3 = hs4[(size_t)(e3 & 0x1FFFFu) * 8 + l8];
        int c4 = l8 * 4;
        if (g0) { unsigned lc = e0 >> 17; float* a = &agg[lc * ND + c4];
                  atomicAdd(a + 0, v0.x); atomicAdd(a + 1, v0.y);
                  atomicAdd(a + 2, v0.z); atomicAdd(a + 3, v0.w); }
        if (g1) { unsigned lc = e1 >> 17; float* a = &agg[lc * ND + c4];
                  atomicAdd(a + 0, v1.x); atomicAdd(a + 1, v1.y);
                  atomicAdd(a + 2, v1.z); atomicAdd(a + 3, v1.w); }
        if (g2) { unsigned lc = e2 >> 17; float* a = &agg[lc * ND + c4];
                  atomicAdd(a + 0, v2.x); atomicAdd(a + 1, v2.y);
                  atomicAdd(a + 2, v2.z); atomicAdd(a + 3, v2.w); }
        if (g3) { unsigned lc = e3 >> 17; float* a = &agg[lc * ND + c4];
                  atomicAdd(a + 0, v3.x); atomicAdd(a + 1, v3.y);
                  atomicAdd(a + 2, v3.z); atomicAdd(a + 3, v3.w); }
    }
    __syncthreads();

    // finalize: 8 groups of 32 lanes, one node each per iter
    int g32 = tid >> 5;
    int ch  = tid & 31;
    int nodebase = b * NPB;
    for (int lc = g32; lc < NPB; lc += 8) {
        int c = nodebase + lc;
        if (c < n) {
            float acc = agg[lc * ND + ch] + hs[(size_t)c * ND + ch];  // edges + self
            float g = fmaxf(dinv[c] * acc + sbg[ch], 0.f);
            float o = sbd[ch];
#pragma unroll
            for (int j = 0; j < ND; ++j) {
                float gj = __shfl(g, j, 32);
                o += gj * sW[j * ND + ch];
            }
            out[(size_t)c * ND + ch] = fmaxf(o, 0.f);
        }
    }
}

extern "C" void kernel_launch(void* const* d_in, const int* in_sizes, int n_in,
                              void* d_out, int out_size, void* d_ws, size_t ws_size,
                              hipStream_t stream) {
    const float* x  = (const float*)d_in[0];
    const int*   ei = (const int*)d_in[1];   // [2, E] flat: row then col
    const float* Wg = (const float*)d_in[2];
    const float* bg = (const float*)d_in[3];
    const float* Wd = (const float*)d_in[4];
    const float* bd = (const float*)d_in[5];
    float* out = (float*)d_out;

    const int n = in_sizes[0] / ID;        // 100000
    const int E = in_sizes[1] / 2;         // 3200000
    const int* erow = ei;
    const int* ecol = ei + E;
    const int B = (n + NPB - 1) / NPB;     // 1563 buckets

    // workspace carve-up
    float*    hs     = (float*)d_ws;                        // n*ND f32   (12.8 MB)
    unsigned* packed = (unsigned*)(hs + (size_t)n * ND);    // E u32      (12.8 MB)
    unsigned* cnt    = packed + (size_t)E;                  // n u32
    float*    dinv   = (float*)(cnt + n);                   // n f32
    unsigned* bsize  = (unsigned*)(dinv + n);               // B u32
    unsigned* boff   = bsize + B;                           // B u32
    unsigned* bcur   = boff + B;                            // B*CPAD u32 (100 KB)

    hipMemsetAsync(cnt, 0, (size_t)n * sizeof(unsigned), stream);
    k_count<<<(E + 255) / 256, 256, 0, stream>>>(ecol, E, cnt);
    k_bsum_dinv<<<B, 64, 0, stream>>>(cnt, n, bsize, dinv);
    k_scan<<<1, 1024, 0, stream>>>(bsize, B, boff, bcur);
    k_gemm<<<(n + 255) / 256, 256, 0, stream>>>(x, Wg, dinv, hs, n);
    k_place<<<(E + EPB - 1) / EPB, 256, 0, stream>>>(erow, ecol, bcur, packed, E, B);
    k_agg<<<B, 256, 0, stream>>>(boff, bsize, packed, hs, dinv, bg, Wd, bd, out, n);
}